// Round 4
// baseline (311.562 us; speedup 1.0000x reference)
//
#include <hip/hip_runtime.h>
#include <math.h>

#define NUM_B 4
#define NUM_N 20000
#define NUM_E 100000
#define DIM 128
#define NH 8
#define NHD 16
#define BN (NUM_B * NUM_N)
#define NB ((BN + 255) / 256)  // 313 scan blocks
#define XPAD 132               // padded LDS row stride (floats)

typedef unsigned short ushort_t;

__device__ inline ushort_t f2bf(float f) {
  unsigned u = __float_as_uint(f);
  unsigned r = (u + 0x7FFFu + ((u >> 16) & 1u)) >> 16;  // RNE
  return (ushort_t)r;
}

// ------------- prep: AqT[h][i] = sum_d Wq[i][h*16+d]*attn_q[h][d] --------
__global__ __launch_bounds__(256) void k_prep(
    const float* __restrict__ Wq, const float* __restrict__ bq,
    const float* __restrict__ Wk, const float* __restrict__ bk,
    const float* __restrict__ attn,
    float* __restrict__ AqT, float* __restrict__ AkT, float* __restrict__ cvec) {
  int t = threadIdx.x;
  for (int idx = t; idx < DIM * NH; idx += 256) {
    int h = idx >> 7, i = idx & 127;
    float sq = 0.f, sk = 0.f;
    for (int d = 0; d < NHD; ++d) {
      sq += Wq[i * DIM + h * NHD + d] * attn[h * 2 * NHD + d];
      sk += Wk[i * DIM + h * NHD + d] * attn[h * 2 * NHD + NHD + d];
    }
    AqT[h * DIM + i] = sq;
    AkT[h * DIM + i] = sk;
  }
  if (t < NH) {
    float cq = 0.f, ck = 0.f;
    for (int d = 0; d < NHD; ++d) {
      cq += bq[t * NHD + d] * attn[t * 2 * NHD + d];
      ck += bk[t * NHD + d] * attn[t * 2 * NHD + NHD + d];
    }
    cvec[t] = cq;
    cvec[NH + t] = ck;
  }
}

// ------------- proj: V(bf16) = X@Wv + bv ; aq = X@Aq + cq ; ak = ... -----
__global__ __launch_bounds__(256) void k_proj(
    const float* __restrict__ X, const float* __restrict__ Wv,
    const float* __restrict__ bv, const float* __restrict__ AqT,
    const float* __restrict__ AkT, const float* __restrict__ cvec,
    float* __restrict__ aq, float* __restrict__ ak, ushort_t* __restrict__ V) {
  __shared__ float xs[64][XPAD];
  int t = threadIdx.x;
  int node0 = blockIdx.x * 64;

  const float4* Xv = (const float4*)(X + (int64_t)node0 * DIM);
  for (int k = t; k < 64 * DIM / 4; k += 256) {
    int n = k >> 5, c = k & 31;
    ((float4*)&xs[n][0])[c] = Xv[k];
  }
  __syncthreads();

  int c = t & 31, g = t >> 5;  // cols 4c..4c+3, rows 8g..8g+7
  float acc[8][4];
#pragma unroll
  for (int r = 0; r < 8; ++r)
#pragma unroll
    for (int q = 0; q < 4; ++q) acc[r][q] = 0.f;

  const float4* Wv4 = (const float4*)Wv;
  for (int i = 0; i < DIM; ++i) {
    float4 w = Wv4[i * 32 + c];
#pragma unroll
    for (int r = 0; r < 8; ++r) {
      float x = xs[g * 8 + r][i];
      acc[r][0] += x * w.x;
      acc[r][1] += x * w.y;
      acc[r][2] += x * w.z;
      acc[r][3] += x * w.w;
    }
  }
  float4 bv4 = ((const float4*)bv)[c];
  ushort4* V4 = (ushort4*)V;
#pragma unroll
  for (int r = 0; r < 8; ++r) {
    ushort4 o;
    o.x = f2bf(acc[r][0] + bv4.x);
    o.y = f2bf(acc[r][1] + bv4.y);
    o.z = f2bf(acc[r][2] + bv4.z);
    o.w = f2bf(acc[r][3] + bv4.w);
    V4[(int64_t)(node0 + g * 8 + r) * 32 + c] = o;
  }

  // aq/ak: 64 nodes x 8 heads, both q and k per task; b128 LDS reads.
  // Pad 132 puts the 8 node-rows on distinct bank groups -> conflict-free.
  for (int task = t; task < 64 * NH; task += 256) {
    int node = task >> 3, h = task & 7;
    float sq = cvec[h], sk = cvec[NH + h];
    const float4* aqw = (const float4*)(AqT + h * DIM);
    const float4* akw = (const float4*)(AkT + h * DIM);
    const float4* xr = (const float4*)&xs[node][0];
#pragma unroll 4
    for (int i4 = 0; i4 < 32; ++i4) {
      float4 x = xr[i4];
      float4 wq = aqw[i4];
      float4 wk = akw[i4];
      sq += x.x * wq.x + x.y * wq.y + x.z * wq.z + x.w * wq.w;
      sk += x.x * wk.x + x.y * wk.y + x.z * wk.z + x.w * wk.w;
    }
    aq[(node0 + node) * NH + h] = sq;
    ak[(node0 + node) * NH + h] = sk;
  }
}

// ------------- CSR build ------------------------------------------------
__global__ __launch_bounds__(256) void k_hist(const int* __restrict__ eidx,
                                              int* __restrict__ counts) {
  int gid = blockIdx.x * 256 + threadIdx.x;
  if (gid >= NUM_B * NUM_E) return;
  int b = gid / NUM_E, e = gid - b * NUM_E;
  int tgt = eidx[b * 2 * NUM_E + NUM_E + e];
  atomicAdd(&counts[b * NUM_N + tgt], 1);
}

__global__ __launch_bounds__(256) void k_scan1(const int* __restrict__ counts,
                                               int* __restrict__ starts,
                                               int* __restrict__ bsums) {
  __shared__ int sh[256];
  int i = blockIdx.x * 256 + threadIdx.x;
  int v = (i < BN) ? counts[i] : 0;
  sh[threadIdx.x] = v;
  __syncthreads();
  for (int off = 1; off < 256; off <<= 1) {
    int t = (threadIdx.x >= off) ? sh[threadIdx.x - off] : 0;
    __syncthreads();
    sh[threadIdx.x] += t;
    __syncthreads();
  }
  if (i < BN) starts[i] = sh[threadIdx.x] - v;
  if (threadIdx.x == 255) bsums[blockIdx.x] = sh[255];
}

__global__ __launch_bounds__(512) void k_scan2(int* __restrict__ bsums) {
  __shared__ int sh[512];
  int t = threadIdx.x;
  int v = (t < NB) ? bsums[t] : 0;
  sh[t] = v;
  __syncthreads();
  for (int off = 1; off < 512; off <<= 1) {
    int u = (t >= off) ? sh[t - off] : 0;
    __syncthreads();
    sh[t] += u;
    __syncthreads();
  }
  if (t < NB) bsums[t] = sh[t] - v;
}

__global__ __launch_bounds__(256) void k_scan3(int* __restrict__ starts,
                                               const int* __restrict__ bsums) {
  int i = blockIdx.x * 256 + threadIdx.x;
  if (i < BN) starts[i] += bsums[blockIdx.x];
}

// scatter src ids into CSR order; bumps starts so afterwards starts[n]=end(n)
__global__ __launch_bounds__(256) void k_scatter(const int* __restrict__ eidx,
                                                 int* __restrict__ starts,
                                                 int* __restrict__ sorted_src) {
  int gid = blockIdx.x * 256 + threadIdx.x;
  if (gid >= NUM_B * NUM_E) return;
  int b = gid / NUM_E, e = gid - b * NUM_E;
  int src = eidx[b * 2 * NUM_E + e];
  int tgt = eidx[b * 2 * NUM_E + NUM_E + e];
  int pos = atomicAdd(&starts[b * NUM_N + tgt], 1);
  sorted_src[pos] = b * NUM_N + src;
}

// ------------- fused gather + Wo GEMM + residual + LayerNorm ------------
// 64 nodes / block. Phase 1: each of 4 waves gathers 16 nodes (lane owns
// dims 2l,2l+1 of head l>>3; exp without max-shift, fp32-safe here), result
// straight into LDS. Phase 2: 8x4 register-tiled GEMM vs Wo + LN.
__global__ __launch_bounds__(256) void k_gat_out(
    const int* __restrict__ sorted_src, const int* __restrict__ ends,
    const int* __restrict__ counts, const float* __restrict__ aq,
    const float* __restrict__ ak, const ushort_t* __restrict__ V,
    const float* __restrict__ X, const float* __restrict__ Wo,
    const float* __restrict__ bo, const float* __restrict__ gamma,
    const float* __restrict__ beta, float* __restrict__ out) {
  __shared__ float as[64][XPAD];
  int t = threadIdx.x;
  int node0 = blockIdx.x * 64;
  int w = t >> 6, lane = t & 63;
  int h = lane >> 3;

  for (int it = 0; it < 16; ++it) {
    int nloc = w * 16 + it;
    int node = node0 + nloc;
    int s1 = ends[node];
    int s0 = s1 - counts[node];
    float aqh = aq[node * NH + h];
    float accx = 0.f, accy = 0.f, den = 0.f;
    for (int p = s0; p < s1; ++p) {
      int sf = sorted_src[p];
      float s = aqh + ak[sf * NH + h];
      s = s > 0.f ? s : 0.2f * s;
      float e = __expf(s);
      unsigned vv = *(const unsigned*)(V + ((int64_t)sf << 7) + 2 * lane);
      float vx = __uint_as_float((vv & 0xFFFFu) << 16);
      float vy = __uint_as_float(vv & 0xFFFF0000u);
      accx += e * vx;
      accy += e * vy;
      den += e;
    }
    float inv = den > 0.f ? 1.0f / den : 0.f;
    *(float2*)&as[nloc][2 * lane] = make_float2(accx * inv, accy * inv);
  }
  __syncthreads();

  int c = t & 31, g = t >> 5;
  float acc[8][4];
#pragma unroll
  for (int r = 0; r < 8; ++r)
#pragma unroll
    for (int q = 0; q < 4; ++q) acc[r][q] = 0.f;

  const float4* Wo4 = (const float4*)Wo;
  for (int i = 0; i < DIM; ++i) {
    float4 wv = Wo4[i * 32 + c];
#pragma unroll
    for (int r = 0; r < 8; ++r) {
      float a = as[g * 8 + r][i];
      acc[r][0] += a * wv.x;
      acc[r][1] += a * wv.y;
      acc[r][2] += a * wv.z;
      acc[r][3] += a * wv.w;
    }
  }

  float4 bo4 = ((const float4*)bo)[c];
  const float4* X4 = (const float4*)X;
  float s1v[8], s2v[8];
#pragma unroll
  for (int r = 0; r < 8; ++r) {
    int row = node0 + g * 8 + r;
    float4 xr = X4[(int64_t)row * 32 + c];
    acc[r][0] += bo4.x + xr.x;
    acc[r][1] += bo4.y + xr.y;
    acc[r][2] += bo4.z + xr.z;
    acc[r][3] += bo4.w + xr.w;
    s1v[r] = acc[r][0] + acc[r][1] + acc[r][2] + acc[r][3];
    s2v[r] = acc[r][0] * acc[r][0] + acc[r][1] * acc[r][1] +
             acc[r][2] * acc[r][2] + acc[r][3] * acc[r][3];
  }
#pragma unroll
  for (int off = 1; off < 32; off <<= 1) {
#pragma unroll
    for (int r = 0; r < 8; ++r) {
      s1v[r] += __shfl_xor(s1v[r], off);
      s2v[r] += __shfl_xor(s2v[r], off);
    }
  }
  float4 gm = ((const float4*)gamma)[c];
  float4 bt = ((const float4*)beta)[c];
  float4* O4 = (float4*)out;
#pragma unroll
  for (int r = 0; r < 8; ++r) {
    float mu = s1v[r] * (1.0f / DIM);
    float var = s2v[r] * (1.0f / DIM) - mu * mu;
    float rs = rsqrtf(var + 1e-5f);
    float4 o;
    o.x = (acc[r][0] - mu) * rs * gm.x + bt.x;
    o.y = (acc[r][1] - mu) * rs * gm.y + bt.y;
    o.z = (acc[r][2] - mu) * rs * gm.z + bt.z;
    o.w = (acc[r][3] - mu) * rs * gm.w + bt.w;
    O4[(int64_t)(node0 + g * 8 + r) * 32 + c] = o;
  }
}

extern "C" void kernel_launch(void* const* d_in, const int* in_sizes, int n_in,
                              void* d_out, int out_size, void* d_ws,
                              size_t ws_size, hipStream_t stream) {
  const float* X     = (const float*)d_in[0];
  const int*   eidx  = (const int*)d_in[1];
  const float* Wq    = (const float*)d_in[2];
  const float* bq    = (const float*)d_in[3];
  const float* Wk    = (const float*)d_in[4];
  const float* bk    = (const float*)d_in[5];
  const float* Wv    = (const float*)d_in[6];
  const float* bv    = (const float*)d_in[7];
  const float* attn  = (const float*)d_in[8];
  const float* Wo    = (const float*)d_in[9];
  const float* bo    = (const float*)d_in[10];
  const float* gamma = (const float*)d_in[11];
  const float* beta  = (const float*)d_in[12];
  float* out = (float*)d_out;

  float* ws   = (float*)d_ws;
  float* AqT  = ws;                      // 1024
  float* AkT  = ws + 1024;               // 1024
  float* cvec = ws + 2048;               // 16
  float* aqv  = ws + 2064;               // BN*NH
  float* akv  = aqv + (int64_t)BN * NH;  // BN*NH
  ushort_t* V = (ushort_t*)(akv + (int64_t)BN * NH);  // BN*DIM bf16
  int* counts     = (int*)((char*)V + (int64_t)BN * DIM * sizeof(ushort_t));
  int* starts     = counts + BN;
  int* bsums      = starts + BN;   // NB (<=320)
  int* sorted_src = bsums + 320;   // B*E

  hipMemsetAsync(counts, 0, (size_t)BN * sizeof(int), stream);
  k_prep<<<1, 256, 0, stream>>>(Wq, bq, Wk, bk, attn, AqT, AkT, cvec);
  k_proj<<<BN / 64, 256, 0, stream>>>(X, Wv, bv, AqT, AkT, cvec, aqv, akv, V);

  int ne = NUM_B * NUM_E;
  k_hist<<<(ne + 255) / 256, 256, 0, stream>>>(eidx, counts);
  k_scan1<<<NB, 256, 0, stream>>>(counts, starts, bsums);
  k_scan2<<<1, 512, 0, stream>>>(bsums);
  k_scan3<<<NB, 256, 0, stream>>>(starts, bsums);
  k_scatter<<<(ne + 255) / 256, 256, 0, stream>>>(eidx, starts, sorted_src);

  k_gat_out<<<BN / 64, 256, 0, stream>>>(sorted_src, starts, counts, aqv, akv,
                                         V, X, Wo, bo, gamma, beta, out);
}

// Round 5
// 262.944 us; speedup vs baseline: 1.1849x; 1.1849x over previous
//
#include <hip/hip_runtime.h>
#include <math.h>

#define NUM_B 4
#define NUM_N 20000
#define NUM_E 100000
#define DIM 128
#define NH 8
#define NHD 16
#define BN (NUM_B * NUM_N)
#define NB ((BN + 255) / 256)  // 313 scan blocks
#define XPAD 132               // padded LDS row stride (floats)

typedef unsigned short ushort_t;

__device__ inline ushort_t f2bf(float f) {
  unsigned u = __float_as_uint(f);
  unsigned r = (u + 0x7FFFu + ((u >> 16) & 1u)) >> 16;  // RNE
  return (ushort_t)r;
}

// ------------- prep: AqT[h][i] = sum_d Wq[i][h*16+d]*attn_q[h][d] --------
__global__ __launch_bounds__(256) void k_prep(
    const float* __restrict__ Wq, const float* __restrict__ bq,
    const float* __restrict__ Wk, const float* __restrict__ bk,
    const float* __restrict__ attn,
    float* __restrict__ AqT, float* __restrict__ AkT, float* __restrict__ cvec) {
  int t = threadIdx.x;
  for (int idx = t; idx < DIM * NH; idx += 256) {
    int h = idx >> 7, i = idx & 127;
    float sq = 0.f, sk = 0.f;
    for (int d = 0; d < NHD; ++d) {
      sq += Wq[i * DIM + h * NHD + d] * attn[h * 2 * NHD + d];
      sk += Wk[i * DIM + h * NHD + d] * attn[h * 2 * NHD + NHD + d];
    }
    AqT[h * DIM + i] = sq;
    AkT[h * DIM + i] = sk;
  }
  if (t < NH) {
    float cq = 0.f, ck = 0.f;
    for (int d = 0; d < NHD; ++d) {
      cq += bq[t * NHD + d] * attn[t * 2 * NHD + d];
      ck += bk[t * NHD + d] * attn[t * 2 * NHD + NHD + d];
    }
    cvec[t] = cq;
    cvec[NH + t] = ck;
  }
}

// ------------- proj: V(bf16) = X@Wv + bv ; aq = X@Aq + cq ; ak = ... -----
__global__ __launch_bounds__(256) void k_proj(
    const float* __restrict__ X, const float* __restrict__ Wv,
    const float* __restrict__ bv, const float* __restrict__ AqT,
    const float* __restrict__ AkT, const float* __restrict__ cvec,
    float* __restrict__ aq, float* __restrict__ ak, ushort_t* __restrict__ V) {
  __shared__ float xs[64][XPAD];
  int t = threadIdx.x;
  int node0 = blockIdx.x * 64;

  const float4* Xv = (const float4*)(X + (int64_t)node0 * DIM);
  for (int k = t; k < 64 * DIM / 4; k += 256) {
    int n = k >> 5, c = k & 31;
    ((float4*)&xs[n][0])[c] = Xv[k];
  }
  __syncthreads();

  int c = t & 31, g = t >> 5;  // cols 4c..4c+3, rows 8g..8g+7
  float acc[8][4];
#pragma unroll
  for (int r = 0; r < 8; ++r)
#pragma unroll
    for (int q = 0; q < 4; ++q) acc[r][q] = 0.f;

  const float4* Wv4 = (const float4*)Wv;
  for (int i = 0; i < DIM; ++i) {
    float4 w = Wv4[i * 32 + c];
#pragma unroll
    for (int r = 0; r < 8; ++r) {
      float x = xs[g * 8 + r][i];
      acc[r][0] += x * w.x;
      acc[r][1] += x * w.y;
      acc[r][2] += x * w.z;
      acc[r][3] += x * w.w;
    }
  }
  float4 bv4 = ((const float4*)bv)[c];
  ushort4* V4 = (ushort4*)V;
#pragma unroll
  for (int r = 0; r < 8; ++r) {
    ushort4 o;
    o.x = f2bf(acc[r][0] + bv4.x);
    o.y = f2bf(acc[r][1] + bv4.y);
    o.z = f2bf(acc[r][2] + bv4.z);
    o.w = f2bf(acc[r][3] + bv4.w);
    V4[(int64_t)(node0 + g * 8 + r) * 32 + c] = o;
  }

  // aq/ak: 64 nodes x 8 heads, both q and k per task; b128 LDS reads.
  for (int task = t; task < 64 * NH; task += 256) {
    int node = task >> 3, h = task & 7;
    float sq = cvec[h], sk = cvec[NH + h];
    const float4* aqw = (const float4*)(AqT + h * DIM);
    const float4* akw = (const float4*)(AkT + h * DIM);
    const float4* xr = (const float4*)&xs[node][0];
#pragma unroll 4
    for (int i4 = 0; i4 < 32; ++i4) {
      float4 x = xr[i4];
      float4 wq = aqw[i4];
      float4 wk = akw[i4];
      sq += x.x * wq.x + x.y * wq.y + x.z * wq.z + x.w * wq.w;
      sk += x.x * wk.x + x.y * wk.y + x.z * wk.z + x.w * wk.w;
    }
    aq[(node0 + node) * NH + h] = sq;
    ak[(node0 + node) * NH + h] = sk;
  }
}

// ------------- CSR build ------------------------------------------------
__global__ __launch_bounds__(256) void k_hist(const int* __restrict__ eidx,
                                              int* __restrict__ counts) {
  int gid = blockIdx.x * 256 + threadIdx.x;
  if (gid >= NUM_B * NUM_E) return;
  int b = gid / NUM_E, e = gid - b * NUM_E;
  int tgt = eidx[b * 2 * NUM_E + NUM_E + e];
  atomicAdd(&counts[b * NUM_N + tgt], 1);
}

__global__ __launch_bounds__(256) void k_scan1(const int* __restrict__ counts,
                                               int* __restrict__ starts,
                                               int* __restrict__ bsums) {
  __shared__ int sh[256];
  int i = blockIdx.x * 256 + threadIdx.x;
  int v = (i < BN) ? counts[i] : 0;
  sh[threadIdx.x] = v;
  __syncthreads();
  for (int off = 1; off < 256; off <<= 1) {
    int t = (threadIdx.x >= off) ? sh[threadIdx.x - off] : 0;
    __syncthreads();
    sh[threadIdx.x] += t;
    __syncthreads();
  }
  if (i < BN) starts[i] = sh[threadIdx.x] - v;
  if (threadIdx.x == 255) bsums[blockIdx.x] = sh[255];
}

__global__ __launch_bounds__(512) void k_scan2(int* __restrict__ bsums) {
  __shared__ int sh[512];
  int t = threadIdx.x;
  int v = (t < NB) ? bsums[t] : 0;
  sh[t] = v;
  __syncthreads();
  for (int off = 1; off < 512; off <<= 1) {
    int u = (t >= off) ? sh[t - off] : 0;
    __syncthreads();
    sh[t] += u;
    __syncthreads();
  }
  if (t < NB) bsums[t] = sh[t] - v;
}

__global__ __launch_bounds__(256) void k_scan3(int* __restrict__ starts,
                                               const int* __restrict__ bsums) {
  int i = blockIdx.x * 256 + threadIdx.x;
  if (i < BN) starts[i] += bsums[blockIdx.x];
}

// scatter src ids into CSR order; bumps starts so afterwards starts[n]=end(n)
__global__ __launch_bounds__(256) void k_scatter(const int* __restrict__ eidx,
                                                 int* __restrict__ starts,
                                                 int* __restrict__ sorted_src) {
  int gid = blockIdx.x * 256 + threadIdx.x;
  if (gid >= NUM_B * NUM_E) return;
  int b = gid / NUM_E, e = gid - b * NUM_E;
  int src = eidx[b * 2 * NUM_E + e];
  int tgt = eidx[b * 2 * NUM_E + NUM_E + e];
  int pos = atomicAdd(&starts[b * NUM_N + tgt], 1);
  sorted_src[pos] = b * NUM_N + src;
}

// ------------- gather: one wave per node, single pass, no atomics -------
// lane owns dims 2l,2l+1 -> head h = l>>3; bf16 V rows (256B coalesced).
// exp without max-shift (w = ex/den is shift-invariant; |s|<~16, fp32-safe).
__global__ __launch_bounds__(256) void k_gather(
    const int* __restrict__ sorted_src, const int* __restrict__ ends,
    const int* __restrict__ counts, const float* __restrict__ aq,
    const float* __restrict__ ak, const ushort_t* __restrict__ V,
    float* __restrict__ out) {
  int tid = threadIdx.x;
  int node = blockIdx.x * 4 + (tid >> 6);
  int lane = tid & 63;
  int h = lane >> 3;
  int s1 = ends[node];
  int s0 = s1 - counts[node];
  float aqh = aq[node * NH + h];

  float accx = 0.f, accy = 0.f, den = 0.f;
  for (int p = s0; p < s1; ++p) {
    int sf = sorted_src[p];
    float s = aqh + ak[sf * NH + h];
    s = s > 0.f ? s : 0.2f * s;
    float e = __expf(s);
    unsigned vv = *(const unsigned*)(V + ((int64_t)sf << 7) + 2 * lane);
    float vx = __uint_as_float((vv & 0xFFFFu) << 16);
    float vy = __uint_as_float(vv & 0xFFFF0000u);
    accx += e * vx;
    accy += e * vy;
    den += e;
  }
  float inv = den > 0.f ? 1.0f / den : 0.f;
  *(float2*)(out + (int64_t)node * DIM + 2 * lane) =
      make_float2(accx * inv, accy * inv);
}

// ------------- epilogue: out = LN(agg @ Wo + bo + X) * gamma + beta -----
__global__ __launch_bounds__(256) void k_out(
    const float* __restrict__ X, const float* __restrict__ Wo,
    const float* __restrict__ bo, const float* __restrict__ gamma,
    const float* __restrict__ beta, float* __restrict__ out) {
  __shared__ float as[64][XPAD];
  int t = threadIdx.x;
  int node0 = blockIdx.x * 64;

  const float4* Av = (const float4*)(out + (int64_t)node0 * DIM);
  for (int k = t; k < 64 * DIM / 4; k += 256) {
    int n = k >> 5, c = k & 31;
    ((float4*)&as[n][0])[c] = Av[k];
  }
  __syncthreads();

  int c = t & 31, g = t >> 5;
  float acc[8][4];
#pragma unroll
  for (int r = 0; r < 8; ++r)
#pragma unroll
    for (int q = 0; q < 4; ++q) acc[r][q] = 0.f;

  const float4* Wo4 = (const float4*)Wo;
  for (int i = 0; i < DIM; ++i) {
    float4 w = Wo4[i * 32 + c];
#pragma unroll
    for (int r = 0; r < 8; ++r) {
      float a = as[g * 8 + r][i];
      acc[r][0] += a * w.x;
      acc[r][1] += a * w.y;
      acc[r][2] += a * w.z;
      acc[r][3] += a * w.w;
    }
  }

  float4 bo4 = ((const float4*)bo)[c];
  const float4* X4 = (const float4*)X;
  float s1v[8], s2v[8];
#pragma unroll
  for (int r = 0; r < 8; ++r) {
    int row = node0 + g * 8 + r;
    float4 xr = X4[(int64_t)row * 32 + c];
    acc[r][0] += bo4.x + xr.x;
    acc[r][1] += bo4.y + xr.y;
    acc[r][2] += bo4.z + xr.z;
    acc[r][3] += bo4.w + xr.w;
    s1v[r] = acc[r][0] + acc[r][1] + acc[r][2] + acc[r][3];
    s2v[r] = acc[r][0] * acc[r][0] + acc[r][1] * acc[r][1] +
             acc[r][2] * acc[r][2] + acc[r][3] * acc[r][3];
  }
#pragma unroll
  for (int off = 1; off < 32; off <<= 1) {
#pragma unroll
    for (int r = 0; r < 8; ++r) {
      s1v[r] += __shfl_xor(s1v[r], off);
      s2v[r] += __shfl_xor(s2v[r], off);
    }
  }
  float4 gm = ((const float4*)gamma)[c];
  float4 bt = ((const float4*)beta)[c];
  float4* O4 = (float4*)out;
#pragma unroll
  for (int r = 0; r < 8; ++r) {
    float mu = s1v[r] * (1.0f / DIM);
    float var = s2v[r] * (1.0f / DIM) - mu * mu;
    float rs = rsqrtf(var + 1e-5f);
    float4 o;
    o.x = (acc[r][0] - mu) * rs * gm.x + bt.x;
    o.y = (acc[r][1] - mu) * rs * gm.y + bt.y;
    o.z = (acc[r][2] - mu) * rs * gm.z + bt.z;
    o.w = (acc[r][3] - mu) * rs * gm.w + bt.w;
    O4[(int64_t)(node0 + g * 8 + r) * 32 + c] = o;
  }
}

extern "C" void kernel_launch(void* const* d_in, const int* in_sizes, int n_in,
                              void* d_out, int out_size, void* d_ws,
                              size_t ws_size, hipStream_t stream) {
  const float* X     = (const float*)d_in[0];
  const int*   eidx  = (const int*)d_in[1];
  const float* Wq    = (const float*)d_in[2];
  const float* bq    = (const float*)d_in[3];
  const float* Wk    = (const float*)d_in[4];
  const float* bk    = (const float*)d_in[5];
  const float* Wv    = (const float*)d_in[6];
  const float* bv    = (const float*)d_in[7];
  const float* attn  = (const float*)d_in[8];
  const float* Wo    = (const float*)d_in[9];
  const float* bo    = (const float*)d_in[10];
  const float* gamma = (const float*)d_in[11];
  const float* beta  = (const float*)d_in[12];
  float* out = (float*)d_out;

  float* ws   = (float*)d_ws;
  float* AqT  = ws;                      // 1024
  float* AkT  = ws + 1024;               // 1024
  float* cvec = ws + 2048;               // 16
  float* aqv  = ws + 2064;               // BN*NH
  float* akv  = aqv + (int64_t)BN * NH;  // BN*NH
  ushort_t* V = (ushort_t*)(akv + (int64_t)BN * NH);  // BN*DIM bf16
  int* counts     = (int*)((char*)V + (int64_t)BN * DIM * sizeof(ushort_t));
  int* starts     = counts + BN;
  int* bsums      = starts + BN;   // NB (<=320)
  int* sorted_src = bsums + 320;   // B*E

  hipMemsetAsync(counts, 0, (size_t)BN * sizeof(int), stream);
  k_prep<<<1, 256, 0, stream>>>(Wq, bq, Wk, bk, attn, AqT, AkT, cvec);
  k_proj<<<BN / 64, 256, 0, stream>>>(X, Wv, bv, AqT, AkT, cvec, aqv, akv, V);

  int ne = NUM_B * NUM_E;
  k_hist<<<(ne + 255) / 256, 256, 0, stream>>>(eidx, counts);
  k_scan1<<<NB, 256, 0, stream>>>(counts, starts, bsums);
  k_scan2<<<1, 512, 0, stream>>>(bsums);
  k_scan3<<<NB, 256, 0, stream>>>(starts, bsums);
  k_scatter<<<(ne + 255) / 256, 256, 0, stream>>>(eidx, starts, sorted_src);

  k_gather<<<BN / 4, 256, 0, stream>>>(sorted_src, starts, counts, aqv, akv, V,
                                       out);
  k_out<<<BN / 64, 256, 0, stream>>>(X, Wo, bo, gamma, beta, out);
}